// Round 2
// baseline (472.284 us; speedup 1.0000x reference)
//
#include <hip/hip_runtime.h>
#include <hip/hip_bf16.h>
#include <stdint.h>

// ---------- helpers ----------
__device__ __forceinline__ uint16_t f2bf(float f) {
    union { float f; uint32_t u; } c; c.f = f;
    uint32_t u = c.u;
    return (uint16_t)((u + 0x7FFFu + ((u >> 16) & 1u)) >> 16);  // RNE
}
__device__ __forceinline__ uint32_t pack2(float a, float b) {
    return (uint32_t)f2bf(a) | ((uint32_t)f2bf(b) << 16);
}

typedef __bf16 bf16x8 __attribute__((ext_vector_type(8)));
typedef float  f32x4  __attribute__((ext_vector_type(4)));

#define GLOAD_LDS16(g, l) __builtin_amdgcn_global_load_lds( \
    (const __attribute__((address_space(1))) void*)(g),     \
    (__attribute__((address_space(3))) void*)(l), 16, 0, 0)

#define FENCE() asm volatile("" ::: "memory")

// ---------- Kernel 1: LayerNorm, fp32 in -> bf16 out. One block per row. ----------
__global__ __launch_bounds__(256) void ln_kernel(
    const float* __restrict__ x, const float* __restrict__ gw,
    const float* __restrict__ gb, uint16_t* __restrict__ y, int D)
{
    const int t = threadIdx.x;
    const size_t row = blockIdx.x;
    const float4* xr = (const float4*)(x + row * (size_t)D);
    float4 v0 = xr[2 * t], v1 = xr[2 * t + 1];

    float s  = v0.x + v0.y + v0.z + v0.w + v1.x + v1.y + v1.z + v1.w;
    float ss = v0.x * v0.x + v0.y * v0.y + v0.z * v0.z + v0.w * v0.w
             + v1.x * v1.x + v1.y * v1.y + v1.z * v1.z + v1.w * v1.w;
#pragma unroll
    for (int off = 32; off > 0; off >>= 1) {
        s  += __shfl_down(s, off);
        ss += __shfl_down(ss, off);
    }
    __shared__ float red[10];
    const int wave = t >> 6, lane = t & 63;
    if (lane == 0) { red[wave] = s; red[4 + wave] = ss; }
    __syncthreads();
    if (t == 0) {
        float S  = red[0] + red[1] + red[2] + red[3];
        float SS = red[4] + red[5] + red[6] + red[7];
        float mu = S / (float)D;
        float var = SS / (float)D - mu * mu;
        red[8] = mu;
        red[9] = rsqrtf(var + 1e-5f);
    }
    __syncthreads();
    const float mu = red[8], rstd = red[9];

    const float4* wr = (const float4*)gw;
    const float4* br = (const float4*)gb;
    float4 w0 = wr[2 * t], w1 = wr[2 * t + 1];
    float4 b0 = br[2 * t], b1 = br[2 * t + 1];

    uint4 ov;
    ov.x = pack2((v0.x - mu) * rstd * w0.x + b0.x, (v0.y - mu) * rstd * w0.y + b0.y);
    ov.y = pack2((v0.z - mu) * rstd * w0.z + b0.z, (v0.w - mu) * rstd * w0.w + b0.w);
    ov.z = pack2((v1.x - mu) * rstd * w1.x + b1.x, (v1.y - mu) * rstd * w1.y + b1.y);
    ov.w = pack2((v1.z - mu) * rstd * w1.z + b1.z, (v1.w - mu) * rstd * w1.w + b1.w);
    ((uint4*)(y + row * (size_t)D))[t] = ov;
}

// ---------- Kernel 2: weights fp32 -> bf16, concat [Wq;Wk;Wv] ----------
__global__ __launch_bounds__(256) void wcvt_kernel(
    const float* __restrict__ wq, const float* __restrict__ wk,
    const float* __restrict__ wv, uint16_t* __restrict__ out)
{
    const size_t i = ((size_t)blockIdx.x * 256 + threadIdx.x) * 8;
    const int which = (int)(i >> 22);            // 2048*2048 = 2^22 per matrix
    const float* src = (which == 0) ? wq : (which == 1) ? wk : wv;
    const size_t off = i & ((1u << 22) - 1);
    float4 a = *(const float4*)(src + off);
    float4 b = *(const float4*)(src + off + 4);
    uint4 ov;
    ov.x = pack2(a.x, a.y);
    ov.y = pack2(a.z, a.w);
    ov.z = pack2(b.x, b.y);
    ov.w = pack2(b.z, b.w);
    *(uint4*)(out + i) = ov;
}

// ---------- Kernel 3: 256x256 tile, BK=64, 8 waves, 8-phase counted-vmcnt ----------
// Template per m201 (plain-HIP 8-phase): T1 XCD swizzle, T2 st_16x32 swizzle
// (pre-swizzled global source, linear global_load_lds dest, swizzled ds_read),
// T3+T4 counted vmcnt(4) only at K-tile boundaries, T5 setprio around MFMA.
// LDS: A[slot][half] 4x16KB at 0, B[slot][half] 4x16KB at 65536. 128 KiB total.

// stage one 128x64 half-tile: 2 x global_load_lds(16B) per thread, linear dest.
#define STAGE_A(H, KT, SL) do {                                               \
    const uint16_t* g_ = gA + (size_t)((H) * 128) * K + (KT) * 64;            \
    char* l_ = (char*)lds + (((SL) * 2 + (H)) * 16384) + t * 16;              \
    GLOAD_LDS16(g_, l_);                                                      \
    GLOAD_LDS16(g_ + (size_t)64 * K, l_ + 8192);                              \
} while (0)

#define STAGE_B(H, KT, SL) do {                                               \
    const uint16_t* g_ = gB + (size_t)((H) * 128) * K + (KT) * 64;            \
    char* l_ = (char*)lds + 65536 + (((SL) * 2 + (H)) * 16384) + t * 16;      \
    GLOAD_LDS16(g_, l_);                                                      \
    GLOAD_LDS16(g_ + (size_t)64 * K, l_ + 8192);                              \
} while (0)

// one phase: ds-read A quadrant (2 m-frags x 2 k-slices), issue stage, barrier,
// lgkmcnt(0), 16 MFMA under setprio, optional vm wait, barrier, compiler fence.
#define PHASE(P, ABASE, STAGE_CODE, PREBAR, TAILWAIT)                         \
  {                                                                           \
    bf16x8 Af[2][2];                                                          \
    _Pragma("unroll") for (int m_ = 0; m_ < 2; ++m_)                          \
      _Pragma("unroll") for (int s_ = 0; s_ < 2; ++s_)                        \
        Af[m_][s_] = *(const bf16x8*)((const char*)lds + (ABASE) + aoff       \
                                      + (2 * (P) + m_) * 2048 + s_ * 64);     \
    STAGE_CODE                                                                \
    PREBAR                                                                    \
    __builtin_amdgcn_s_barrier();                                             \
    asm volatile("s_waitcnt lgkmcnt(0)" ::: "memory");                        \
    __builtin_amdgcn_s_setprio(1);                                            \
    _Pragma("unroll") for (int s_ = 0; s_ < 2; ++s_)                          \
      _Pragma("unroll") for (int m_ = 0; m_ < 2; ++m_)                        \
        _Pragma("unroll") for (int j_ = 0; j_ < 4; ++j_)                      \
          acc[2 * (P) + m_][j_] = __builtin_amdgcn_mfma_f32_16x16x32_bf16(    \
              Af[m_][s_], Bf[j_][s_], acc[2 * (P) + m_][j_], 0, 0, 0);        \
    __builtin_amdgcn_s_setprio(0);                                            \
    TAILWAIT                                                                  \
    __builtin_amdgcn_s_barrier();                                             \
    FENCE();                                                                  \
  }

// one K-tile = 4 phases. Stage schedule: p0/p1 -> A halves of (KT+1) into the
// other slot; p2/p3 -> B halves of (KT+2) into this slot (B slot is free after
// this tile's top-of-tile B-reads, which all waves complete before phase-1's
// end barrier). vmcnt(4) at p3 leaves exactly the 2 B half-tiles of (KT+2)
// in flight; everything the next tile reads has landed.
#define KTILE(SLOT, KT, SA, SB, TAILWAIT)                                     \
  {                                                                           \
    const int ab_ = ((SLOT) * 2 + wr) * 16384;                                \
    const int bb_ = 65536 + ((SLOT) * 2 + (wc >> 1)) * 16384;                 \
    bf16x8 Bf[4][2];                                                          \
    _Pragma("unroll") for (int j_ = 0; j_ < 4; ++j_)                          \
      _Pragma("unroll") for (int s_ = 0; s_ < 2; ++s_)                        \
        Bf[j_][s_] = *(const bf16x8*)((const char*)lds + bb_ + boff           \
                                      + j_ * 2048 + s_ * 64);                 \
    PHASE(0, ab_, { if (SA) STAGE_A(0, (KT) + 1, (SLOT) ^ 1); },              \
          asm volatile("s_waitcnt lgkmcnt(8)" ::: "memory");, )               \
    PHASE(1, ab_, { if (SA) STAGE_A(1, (KT) + 1, (SLOT) ^ 1); }, , )          \
    PHASE(2, ab_, { if (SB) STAGE_B(0, (KT) + 2, (SLOT)); }, , )              \
    PHASE(3, ab_, { if (SB) STAGE_B(1, (KT) + 2, (SLOT)); }, , TAILWAIT)      \
  }

__global__ __launch_bounds__(512, 2) void qkv_gemm256(
    const uint16_t* __restrict__ A, const uint16_t* __restrict__ W,
    const float* __restrict__ Bq, const float* __restrict__ Bk,
    const float* __restrict__ Bv, float* __restrict__ C,
    int M, int N, int K)
{
    (void)M;
    extern __shared__ uint16_t lds[];
    const int t = threadIdx.x;
    const int lane = t & 63, wid = t >> 6;
    const int wr = wid >> 2, wc = wid & 3;          // 2 x 4 wave grid
    const int fr = lane & 15;
    const int fq2 = (lane >> 4) * 16;               // k-frag byte offset {0,16,32,48}

    // T1: bijective XCD swizzle (gridDim.x % 8 == 0 here)
    const int nbt = N >> 8;                         // 24 col-tiles
    const int nwg = gridDim.x;
    int bid = blockIdx.x;
    int swz = (nwg & 7) ? bid : ((bid & 7) * (nwg >> 3) + (bid >> 3));
    const int mb = swz / nbt, nb = swz % nbt;

    // read-side st_16x32 swizzle: logical byte q -> LDS byte q ^ ((q>>9)&1)<<5.
    // bit9 of q == bit2 of the row == fr&4. bit5 of q comes ONLY from fq2
    // (s_*64 is bit6, rows are bits>=7), so the XOR must be applied to fq2 —
    // R0's additive "+sx" carried into bit6 for lanes 32-63 (fq2 in {32,48}).
    const int sx = (fr & 4) ? 32 : 0;
    const int koff = fq2 ^ sx;                      // XOR, not add
    const int aoff = fr * 128 + koff;
    const int boff = ((wc & 1) * 64 + fr) * 128 + koff;

    // write-side pre-swizzled global source: LDS byte p=t*16 holds logical
    // q = p ^ ((p>>9)&1)<<5 -> row t>>3, col ((t&7)*8) ^ (bit5(t)?16:0)
    const int srow = t >> 3;
    const int scol = ((t & 7) * 8) ^ (((t >> 5) & 1) << 4);
    const uint16_t* gA = A + (size_t)(mb * 256 + srow) * K + scol;
    const uint16_t* gB = W + (size_t)(nb * 256 + srow) * K + scol;

    f32x4 acc[8][4] = {};
    const int NT = K >> 6;                          // 32 K-tiles

    // prologue: B(0)->Bslot0, A(0)->Aslot0, B(1)->Bslot1; keep B(1) in flight
    STAGE_B(0, 0, 0); STAGE_B(1, 0, 0);
    STAGE_A(0, 0, 0); STAGE_A(1, 0, 0);
    STAGE_B(0, 1, 1); STAGE_B(1, 1, 1);
    asm volatile("s_waitcnt vmcnt(4)" ::: "memory");
    __builtin_amdgcn_s_barrier();
    FENCE();

#pragma unroll 1
    for (int i = 0; i < (NT >> 1) - 1; ++i) {
        const int k0 = i << 1;
        KTILE(0, k0,     1, 1, asm volatile("s_waitcnt vmcnt(4)" ::: "memory");)
        KTILE(1, k0 + 1, 1, 1, asm volatile("s_waitcnt vmcnt(4)" ::: "memory");)
    }
    // tail: tile NT-2 stages A(NT-1) only, drain; tile NT-1 pure compute
    KTILE(0, NT - 2, 1, 0, asm volatile("s_waitcnt vmcnt(0)" ::: "memory");)
    KTILE(1, NT - 1, 0, 0, )

    // epilogue: C/D layout row=(lane>>4)*4+reg, col=lane&15. fp32 stores + bias.
    const int r0 = mb * 256 + wr * 128 + (lane >> 4) * 4;
    const int c0 = nb * 256 + wc * 64 + fr;
    const float* bp = (nb < 8) ? Bq : (nb < 16) ? Bk : Bv;
    const int cb = (nb & 7) * 256 + wc * 64 + fr;
    float bj[4];
#pragma unroll
    for (int j = 0; j < 4; ++j) bj[j] = bp[cb + j * 16];
#pragma unroll
    for (int i = 0; i < 8; ++i)
#pragma unroll
        for (int j = 0; j < 4; ++j)
#pragma unroll
            for (int r = 0; r < 4; ++r)
                C[(size_t)(r0 + i * 16 + r) * N + c0 + j * 16] = acc[i][j][r] + bj[j];
}

extern "C" void kernel_launch(void* const* d_in, const int* in_sizes, int n_in,
                              void* d_out, int out_size, void* d_ws, size_t ws_size,
                              hipStream_t stream) {
    const float* x  = (const float*)d_in[0];
    const float* nw = (const float*)d_in[1];
    const float* nb = (const float*)d_in[2];
    const float* wq = (const float*)d_in[3];
    const float* bq = (const float*)d_in[4];
    const float* wk = (const float*)d_in[5];
    const float* bk = (const float*)d_in[6];
    const float* wv = (const float*)d_in[7];
    const float* bv = (const float*)d_in[8];

    const int D = in_sizes[1];        // 2048
    const int M = in_sizes[0] / D;    // 8192 (B*S)
    const int N = 3 * D;              // 6144

    static bool attr_done = false;
    if (!attr_done) {
        hipFuncSetAttribute((const void*)qkv_gemm256,
                            hipFuncAttributeMaxDynamicSharedMemorySize, 131072);
        attr_done = true;
    }

    // ws layout: [normed bf16: M*D] [Wcat bf16: N*D]
    uint16_t* normed = (uint16_t*)d_ws;
    uint16_t* wcat   = normed + (size_t)M * D;

    ln_kernel<<<M, 256, 0, stream>>>(x, nw, nb, normed, D);
    wcvt_kernel<<<((size_t)N * D) / (256 * 8), 256, 0, stream>>>(wq, wk, wv, wcat);
    const int grid = (M / 256) * (N / 256);         // 768, %8==0
    qkv_gemm256<<<grid, 512, 131072, stream>>>(normed, wcat, bq, bk, bv,
                                               (float*)d_out, M, N, D);
}

// Round 5
// 464.177 us; speedup vs baseline: 1.0175x; 1.0175x over previous
//
#include <hip/hip_runtime.h>
#include <hip/hip_bf16.h>
#include <stdint.h>

// ---------- helpers ----------
__device__ __forceinline__ uint16_t f2bf(float f) {
    union { float f; uint32_t u; } c; c.f = f;
    uint32_t u = c.u;
    return (uint16_t)((u + 0x7FFFu + ((u >> 16) & 1u)) >> 16);  // RNE
}
__device__ __forceinline__ uint32_t pack2(float a, float b) {
    return (uint32_t)f2bf(a) | ((uint32_t)f2bf(b) << 16);
}

typedef __bf16 bf16x8 __attribute__((ext_vector_type(8)));
typedef float  f32x4  __attribute__((ext_vector_type(4)));

#define GLOAD_LDS16(g, l) __builtin_amdgcn_global_load_lds( \
    (const __attribute__((address_space(1))) void*)(g),     \
    (__attribute__((address_space(3))) void*)(l), 16, 0, 0)

#define FENCE() asm volatile("" ::: "memory")

// ---------- Kernel 1: LayerNorm, fp32 in -> bf16 out. One block per row. ----------
__global__ __launch_bounds__(256) void ln_kernel(
    const float* __restrict__ x, const float* __restrict__ gw,
    const float* __restrict__ gb, uint16_t* __restrict__ y, int D)
{
    const int t = threadIdx.x;
    const size_t row = blockIdx.x;
    const float4* xr = (const float4*)(x + row * (size_t)D);
    float4 v0 = xr[2 * t], v1 = xr[2 * t + 1];

    float s  = v0.x + v0.y + v0.z + v0.w + v1.x + v1.y + v1.z + v1.w;
    float ss = v0.x * v0.x + v0.y * v0.y + v0.z * v0.z + v0.w * v0.w
             + v1.x * v1.x + v1.y * v1.y + v1.z * v1.z + v1.w * v1.w;
#pragma unroll
    for (int off = 32; off > 0; off >>= 1) {
        s  += __shfl_down(s, off);
        ss += __shfl_down(ss, off);
    }
    __shared__ float red[10];
    const int wave = t >> 6, lane = t & 63;
    if (lane == 0) { red[wave] = s; red[4 + wave] = ss; }
    __syncthreads();
    if (t == 0) {
        float S  = red[0] + red[1] + red[2] + red[3];
        float SS = red[4] + red[5] + red[6] + red[7];
        float mu = S / (float)D;
        float var = SS / (float)D - mu * mu;
        red[8] = mu;
        red[9] = rsqrtf(var + 1e-5f);
    }
    __syncthreads();
    const float mu = red[8], rstd = red[9];

    const float4* wr = (const float4*)gw;
    const float4* br = (const float4*)gb;
    float4 w0 = wr[2 * t], w1 = wr[2 * t + 1];
    float4 b0 = br[2 * t], b1 = br[2 * t + 1];

    uint4 ov;
    ov.x = pack2((v0.x - mu) * rstd * w0.x + b0.x, (v0.y - mu) * rstd * w0.y + b0.y);
    ov.y = pack2((v0.z - mu) * rstd * w0.z + b0.z, (v0.w - mu) * rstd * w0.w + b0.w);
    ov.z = pack2((v1.x - mu) * rstd * w1.x + b1.x, (v1.y - mu) * rstd * w1.y + b1.y);
    ov.w = pack2((v1.z - mu) * rstd * w1.z + b1.z, (v1.w - mu) * rstd * w1.w + b1.w);
    ((uint4*)(y + row * (size_t)D))[t] = ov;
}

// ---------- Kernel 2: weights fp32 -> bf16, concat [Wq;Wk;Wv] ----------
__global__ __launch_bounds__(256) void wcvt_kernel(
    const float* __restrict__ wq, const float* __restrict__ wk,
    const float* __restrict__ wv, uint16_t* __restrict__ out)
{
    const size_t i = ((size_t)blockIdx.x * 256 + threadIdx.x) * 8;
    const int which = (int)(i >> 22);            // 2048*2048 = 2^22 per matrix
    const float* src = (which == 0) ? wq : (which == 1) ? wk : wv;
    const size_t off = i & ((1u << 22) - 1);
    float4 a = *(const float4*)(src + off);
    float4 b = *(const float4*)(src + off + 4);
    uint4 ov;
    ov.x = pack2(a.x, a.y);
    ov.y = pack2(a.z, a.w);
    ov.z = pack2(b.x, b.y);
    ov.w = pack2(b.z, b.w);
    *(uint4*)(out + i) = ov;
}

// ---------- Kernel 3: 256x256 tile, BK=64, 8 waves, 8-phase counted-vmcnt ----------
// T1 XCD swizzle + within-XCD 4mb x 8nb band reorder (L2 working set 26->12MB),
// T2 full 3-bit XOR swizzle byte ^= (row&7)<<4 (R2's 1-bit version left 16-way
// conflicts: read offsets mod 128 only covered {0,16,32,48} -> banks 0-15),
// T3+T4 counted vmcnt(4) at K-tile boundaries only, T5 setprio around MFMA.
// LDS: A[slot][half] 4x16KB at 0, B[slot][half] 4x16KB at 65536. 128 KiB total.

// stage one 128x64 half-tile: 2 x global_load_lds(16B) per thread, linear dest.
#define STAGE_A(H, KT, SL) do {                                               \
    const uint16_t* g_ = gA + (size_t)((H) * 128) * K + (KT) * 64;            \
    char* l_ = (char*)lds + (((SL) * 2 + (H)) * 16384) + t * 16;              \
    GLOAD_LDS16(g_, l_);                                                      \
    GLOAD_LDS16(g_ + (size_t)64 * K, l_ + 8192);                              \
} while (0)

#define STAGE_B(H, KT, SL) do {                                               \
    const uint16_t* g_ = gB + (size_t)((H) * 128) * K + (KT) * 64;            \
    char* l_ = (char*)lds + 65536 + (((SL) * 2 + (H)) * 16384) + t * 16;      \
    GLOAD_LDS16(g_, l_);                                                      \
    GLOAD_LDS16(g_ + (size_t)64 * K, l_ + 8192);                              \
} while (0)

// one phase: ds-read A quadrant (2 m-frags x 2 k-slices), issue stage, barrier,
// lgkmcnt(0), 16 MFMA under setprio, optional vm wait, barrier, compiler fence.
// k-slice term s_*64 toggles byte bit6 which participates in the swizzle XOR,
// so it must be XORed (aoff ^ (s_<<6)), never added.
#define PHASE(P, ABASE, STAGE_CODE, PREBAR, TAILWAIT)                         \
  {                                                                           \
    bf16x8 Af[2][2];                                                          \
    _Pragma("unroll") for (int m_ = 0; m_ < 2; ++m_)                          \
      _Pragma("unroll") for (int s_ = 0; s_ < 2; ++s_)                        \
        Af[m_][s_] = *(const bf16x8*)((const char*)lds + (ABASE)              \
                                      + (aoff ^ (s_ << 6))                    \
                                      + (2 * (P) + m_) * 2048);               \
    STAGE_CODE                                                                \
    PREBAR                                                                    \
    __builtin_amdgcn_s_barrier();                                             \
    asm volatile("s_waitcnt lgkmcnt(0)" ::: "memory");                        \
    __builtin_amdgcn_s_setprio(1);                                            \
    _Pragma("unroll") for (int s_ = 0; s_ < 2; ++s_)                          \
      _Pragma("unroll") for (int m_ = 0; m_ < 2; ++m_)                        \
        _Pragma("unroll") for (int j_ = 0; j_ < 4; ++j_)                      \
          acc[2 * (P) + m_][j_] = __builtin_amdgcn_mfma_f32_16x16x32_bf16(    \
              Af[m_][s_], Bf[j_][s_], acc[2 * (P) + m_][j_], 0, 0, 0);        \
    __builtin_amdgcn_s_setprio(0);                                            \
    TAILWAIT                                                                  \
    __builtin_amdgcn_s_barrier();                                             \
    FENCE();                                                                  \
  }

// one K-tile = 4 phases. Stage schedule: p0/p1 -> A halves of (KT+1) into the
// other slot; p2/p3 -> B halves of (KT+2) into this slot (safe: every wave's
// B-reads complete at its p0 lgkmcnt(0), two barriers before any p2 DMA
// issue). vmcnt(4) at p3 leaves exactly the 4 B(KT+2) loads in flight.
#define KTILE(SLOT, KT, SA, SB, TAILWAIT)                                     \
  {                                                                           \
    const int ab_ = ((SLOT) * 2 + wr) * 16384;                                \
    const int bb_ = 65536 + ((SLOT) * 2 + (wc >> 1)) * 16384;                 \
    bf16x8 Bf[4][2];                                                          \
    _Pragma("unroll") for (int j_ = 0; j_ < 4; ++j_)                          \
      _Pragma("unroll") for (int s_ = 0; s_ < 2; ++s_)                        \
        Bf[j_][s_] = *(const bf16x8*)((const char*)lds + bb_                  \
                                      + (boff ^ (s_ << 6)) + j_ * 2048);      \
    PHASE(0, ab_, { if (SA) STAGE_A(0, (KT) + 1, (SLOT) ^ 1); },              \
          asm volatile("s_waitcnt lgkmcnt(8)" ::: "memory");, )               \
    PHASE(1, ab_, { if (SA) STAGE_A(1, (KT) + 1, (SLOT) ^ 1); }, , )          \
    PHASE(2, ab_, { if (SB) STAGE_B(0, (KT) + 2, (SLOT)); }, , )              \
    PHASE(3, ab_, { if (SB) STAGE_B(1, (KT) + 2, (SLOT)); }, , TAILWAIT)      \
  }

__global__ __launch_bounds__(512, 2) void qkv_gemm256(
    const uint16_t* __restrict__ A, const uint16_t* __restrict__ W,
    const float* __restrict__ Bq, const float* __restrict__ Bk,
    const float* __restrict__ Bv, float* __restrict__ C,
    int M, int N, int K)
{
    (void)M;
    extern __shared__ uint16_t lds[];
    const int t = threadIdx.x;
    const int lane = t & 63, wid = t >> 6;
    const int wr = wid >> 2, wc = wid & 3;          // 2 x 4 wave grid
    const int fr = lane & 15;
    const int fq2 = (lane >> 4) * 16;               // k-frag byte offset {0,16,32,48}

    // T1: XCD swizzle + within-XCD band reorder. Each XCD chunk = 96 tiles
    // (4 mb x 24 nb); bands of 32 blocks = 4mb x 8nb so the ~32 concurrently
    // resident blocks per XCD share a 12MB (4MB A + 8MB W) panel working set.
    const int nbt = N >> 8;                         // 24 col-tiles
    const int nwg = gridDim.x;
    int mb, nb;
    if ((nwg & 7) == 0) {
        const int cpx = nwg >> 3;                   // 96 tiles per XCD
        const int xcd = blockIdx.x & 7, ti = blockIdx.x >> 3;
        if (cpx % nbt == 0 && (nbt & 7) == 0) {
            const int band = ti >> 5, r = ti & 31;
            mb = xcd * (cpx / nbt) + (r >> 3);
            nb = (band << 3) + (r & 7);
        } else {
            const int swz = xcd * cpx + ti;
            mb = swz / nbt; nb = swz % nbt;
        }
    } else {
        mb = blockIdx.x / nbt; nb = blockIdx.x % nbt;
    }

    // read-side swizzle: logical byte q -> LDS byte q ^ ((row&7)<<4), where
    // row = q>>7 (128B rows) and row&7 == fr&7 for every fragment (fragment
    // row bases are multiples of 16). Spreads the 8 column slots of each
    // 8-row stripe across all 32 banks: 2 lanes/bank (free).
    const int kbase = fq2 ^ ((fr & 7) << 4);
    const int aoff = fr * 128 + kbase;
    const int boff = ((wc & 1) * 64 + fr) * 128 + kbase;

    // write-side pre-swizzled global source: linear LDS dest byte p = t*16
    // holds logical q = p ^ ((p>>7 & 7)<<4) -> row t>>3,
    // col elements (((t&7) ^ ((t>>3)&7)) * 8). Same involution as read side.
    const int srow = t >> 3;
    const int scol = (((t & 7) ^ ((t >> 3) & 7)) << 3);
    const uint16_t* gA = A + (size_t)(mb * 256 + srow) * K + scol;
    const uint16_t* gB = W + (size_t)(nb * 256 + srow) * K + scol;

    f32x4 acc[8][4] = {};
    const int NT = K >> 6;                          // 32 K-tiles

    // prologue: B(0)->Bslot0, A(0)->Aslot0, B(1)->Bslot1; keep B(1) in flight
    STAGE_B(0, 0, 0); STAGE_B(1, 0, 0);
    STAGE_A(0, 0, 0); STAGE_A(1, 0, 0);
    STAGE_B(0, 1, 1); STAGE_B(1, 1, 1);
    asm volatile("s_waitcnt vmcnt(4)" ::: "memory");
    __builtin_amdgcn_s_barrier();
    FENCE();

#pragma unroll 1
    for (int i = 0; i < (NT >> 1) - 1; ++i) {
        const int k0 = i << 1;
        KTILE(0, k0,     1, 1, asm volatile("s_waitcnt vmcnt(4)" ::: "memory");)
        KTILE(1, k0 + 1, 1, 1, asm volatile("s_waitcnt vmcnt(4)" ::: "memory");)
    }
    // tail: tile NT-2 stages A(NT-1) only, drain; tile NT-1 pure compute
    KTILE(0, NT - 2, 1, 0, asm volatile("s_waitcnt vmcnt(0)" ::: "memory");)
    KTILE(1, NT - 1, 0, 0, )

    // epilogue: C/D layout row=(lane>>4)*4+reg, col=lane&15. fp32 stores + bias.
    const int r0 = mb * 256 + wr * 128 + (lane >> 4) * 4;
    const int c0 = nb * 256 + wc * 64 + fr;
    const float* bp = (nb < 8) ? Bq : (nb < 16) ? Bk : Bv;
    const int cb = (nb & 7) * 256 + wc * 64 + fr;
    float bj[4];
#pragma unroll
    for (int j = 0; j < 4; ++j) bj[j] = bp[cb + j * 16];
#pragma unroll
    for (int i = 0; i < 8; ++i)
#pragma unroll
        for (int j = 0; j < 4; ++j)
#pragma unroll
            for (int r = 0; r < 4; ++r)
                C[(size_t)(r0 + i * 16 + r) * N + c0 + j * 16] = acc[i][j][r] + bj[j];
}

extern "C" void kernel_launch(void* const* d_in, const int* in_sizes, int n_in,
                              void* d_out, int out_size, void* d_ws, size_t ws_size,
                              hipStream_t stream) {
    const float* x  = (const float*)d_in[0];
    const float* nw = (const float*)d_in[1];
    const float* nb = (const float*)d_in[2];
    const float* wq = (const float*)d_in[3];
    const float* bq = (const float*)d_in[4];
    const float* wk = (const float*)d_in[5];
    const float* bk = (const float*)d_in[6];
    const float* wv = (const float*)d_in[7];
    const float* bv = (const float*)d_in[8];

    const int D = in_sizes[1];        // 2048
    const int M = in_sizes[0] / D;    // 8192 (B*S)
    const int N = 3 * D;              // 6144

    static bool attr_done = false;
    if (!attr_done) {
        hipFuncSetAttribute((const void*)qkv_gemm256,
                            hipFuncAttributeMaxDynamicSharedMemorySize, 131072);
        attr_done = true;
    }

    // ws layout: [normed bf16: M*D] [Wcat bf16: N*D]
    uint16_t* normed = (uint16_t*)d_ws;
    uint16_t* wcat   = normed + (size_t)M * D;

    ln_kernel<<<M, 256, 0, stream>>>(x, nw, nb, normed, D);
    wcvt_kernel<<<((size_t)N * D) / (256 * 8), 256, 0, stream>>>(wq, wk, wv, wcat);
    const int grid = (M / 256) * (N / 256);          // 768, %8==0
    qkv_gemm256<<<grid, 512, 131072, stream>>>(normed, wcat, bq, bk, bv,
                                               (float*)d_out, M, N, D);
}

// Round 6
// 457.891 us; speedup vs baseline: 1.0314x; 1.0137x over previous
//
#include <hip/hip_runtime.h>
#include <hip/hip_bf16.h>
#include <stdint.h>

// ---------- helpers ----------
__device__ __forceinline__ uint16_t f2bf(float f) {
    union { float f; uint32_t u; } c; c.f = f;
    uint32_t u = c.u;
    return (uint16_t)((u + 0x7FFFu + ((u >> 16) & 1u)) >> 16);  // RNE
}
__device__ __forceinline__ uint32_t pack2(float a, float b) {
    return (uint32_t)f2bf(a) | ((uint32_t)f2bf(b) << 16);
}

typedef __bf16 bf16x8 __attribute__((ext_vector_type(8)));
typedef float  f32x4  __attribute__((ext_vector_type(4)));

#define GLOAD_LDS16(g, l) __builtin_amdgcn_global_load_lds( \
    (const __attribute__((address_space(1))) void*)(g),     \
    (__attribute__((address_space(3))) void*)(l), 16, 0, 0)

#define FENCE() asm volatile("" ::: "memory")

// ---------- Kernel 1: LayerNorm, fp32 in -> bf16 out. One block per row. ----------
__global__ __launch_bounds__(256) void ln_kernel(
    const float* __restrict__ x, const float* __restrict__ gw,
    const float* __restrict__ gb, uint16_t* __restrict__ y, int D)
{
    const int t = threadIdx.x;
    const size_t row = blockIdx.x;
    const float4* xr = (const float4*)(x + row * (size_t)D);
    float4 v0 = xr[2 * t], v1 = xr[2 * t + 1];

    float s  = v0.x + v0.y + v0.z + v0.w + v1.x + v1.y + v1.z + v1.w;
    float ss = v0.x * v0.x + v0.y * v0.y + v0.z * v0.z + v0.w * v0.w
             + v1.x * v1.x + v1.y * v1.y + v1.z * v1.z + v1.w * v1.w;
#pragma unroll
    for (int off = 32; off > 0; off >>= 1) {
        s  += __shfl_down(s, off);
        ss += __shfl_down(ss, off);
    }
    __shared__ float red[10];
    const int wave = t >> 6, lane = t & 63;
    if (lane == 0) { red[wave] = s; red[4 + wave] = ss; }
    __syncthreads();
    if (t == 0) {
        float S  = red[0] + red[1] + red[2] + red[3];
        float SS = red[4] + red[5] + red[6] + red[7];
        float mu = S / (float)D;
        float var = SS / (float)D - mu * mu;
        red[8] = mu;
        red[9] = rsqrtf(var + 1e-5f);
    }
    __syncthreads();
    const float mu = red[8], rstd = red[9];

    const float4* wr = (const float4*)gw;
    const float4* br = (const float4*)gb;
    float4 w0 = wr[2 * t], w1 = wr[2 * t + 1];
    float4 b0 = br[2 * t], b1 = br[2 * t + 1];

    uint4 ov;
    ov.x = pack2((v0.x - mu) * rstd * w0.x + b0.x, (v0.y - mu) * rstd * w0.y + b0.y);
    ov.y = pack2((v0.z - mu) * rstd * w0.z + b0.z, (v0.w - mu) * rstd * w0.w + b0.w);
    ov.z = pack2((v1.x - mu) * rstd * w1.x + b1.x, (v1.y - mu) * rstd * w1.y + b1.y);
    ov.w = pack2((v1.z - mu) * rstd * w1.z + b1.z, (v1.w - mu) * rstd * w1.w + b1.w);
    ((uint4*)(y + row * (size_t)D))[t] = ov;
}

// ---------- Kernel 2: weights fp32 -> bf16, concat [Wq;Wk;Wv] ----------
__global__ __launch_bounds__(256) void wcvt_kernel(
    const float* __restrict__ wq, const float* __restrict__ wk,
    const float* __restrict__ wv, uint16_t* __restrict__ out)
{
    const size_t i = ((size_t)blockIdx.x * 256 + threadIdx.x) * 8;
    const int which = (int)(i >> 22);            // 2048*2048 = 2^22 per matrix
    const float* src = (which == 0) ? wq : (which == 1) ? wk : wv;
    const size_t off = i & ((1u << 22) - 1);
    float4 a = *(const float4*)(src + off);
    float4 b = *(const float4*)(src + off + 4);
    uint4 ov;
    ov.x = pack2(a.x, a.y);
    ov.y = pack2(a.z, a.w);
    ov.z = pack2(b.x, b.y);
    ov.w = pack2(b.z, b.w);
    *(uint4*)(out + i) = ov;
}

// ---------- Kernel 3: 256x256 tile, BK=64, 8 waves, 8-phase counted-vmcnt ----------
// R5 found: MfmaUtil 44% == MFMA/(MFMA + serialized LDS reads). This version
// pipelines ds_reads one phase ahead (register dbuf AfA/AfB; B + first two A
// quads at tile entry) so LDS read latency hides under the MFMA cluster.
// Compiler inserts precise lgkmcnt before first use (plain loads -> dataflow).
// T1 XCD swizzle + band reorder, T2 3-bit XOR swizzle (0 conflicts, R5),
// T3+T4 counted vmcnt(4) at K-tile boundaries, T5 setprio around MFMA.
// LDS: A[slot][half] 4x16KB at 0, B[slot][half] 4x16KB at 65536. 128 KiB.

#define STAGE_A(H, KT, SL) do {                                               \
    const uint16_t* g_ = gA + (size_t)((H) * 128) * K + (KT) * 64;            \
    char* l_ = (char*)lds + (((SL) * 2 + (H)) * 16384) + t * 16;              \
    GLOAD_LDS16(g_, l_);                                                      \
    GLOAD_LDS16(g_ + (size_t)64 * K, l_ + 8192);                              \
} while (0)

#define STAGE_B(H, KT, SL) do {                                               \
    const uint16_t* g_ = gB + (size_t)((H) * 128) * K + (KT) * 64;            \
    char* l_ = (char*)lds + 65536 + (((SL) * 2 + (H)) * 16384) + t * 16;      \
    GLOAD_LDS16(g_, l_);                                                      \
    GLOAD_LDS16(g_ + (size_t)64 * K, l_ + 8192);                              \
} while (0)

// read one A quad (phase P: m-frags 2P, 2P+1; 2 k-slices) into buf
#define DS_READ_A(buf, P)                                                     \
    _Pragma("unroll") for (int m_ = 0; m_ < 2; ++m_)                          \
      _Pragma("unroll") for (int s_ = 0; s_ < 2; ++s_)                        \
        buf[m_][s_] = *(const bf16x8*)((const char*)lds + ab_                 \
                                       + (aoff ^ (s_ << 6))                   \
                                       + (2 * (P) + m_) * 2048);

#define DS_READ_BF()                                                          \
    _Pragma("unroll") for (int j_ = 0; j_ < 4; ++j_)                          \
      _Pragma("unroll") for (int s_ = 0; s_ < 2; ++s_)                        \
        Bf[j_][s_] = *(const bf16x8*)((const char*)lds + bb_                  \
                                      + (boff ^ (s_ << 6)) + j_ * 2048);

#define MFMA16(P, buf)                                                        \
    __builtin_amdgcn_s_setprio(1);                                            \
    _Pragma("unroll") for (int s_ = 0; s_ < 2; ++s_)                          \
      _Pragma("unroll") for (int m_ = 0; m_ < 2; ++m_)                        \
        _Pragma("unroll") for (int j_ = 0; j_ < 4; ++j_)                      \
          acc[2 * (P) + m_][j_] = __builtin_amdgcn_mfma_f32_16x16x32_bf16(    \
              buf[m_][s_], Bf[j_][s_], acc[2 * (P) + m_][j_], 0, 0, 0);       \
    __builtin_amdgcn_s_setprio(0);

// one K-tile = 4 phases; each phase issues NEXT phase's A-quad reads, then
// stage DMA, FENCE (pin issue point), barrier, MFMA on the PREVIOUS phase's
// buffer. Stage schedule / vmcnt accounting identical to R5 (verified):
// p0/p1 stage A(KT+1) -> other slot, p2/p3 stage B(KT+2) -> this slot,
// vmcnt(4) at p3 leaves exactly the 4 B(KT+2) loads in flight.
#define KTILE(SLOT, KT, SA, SB, TAILWAIT)                                     \
  {                                                                           \
    const int ab_ = ((SLOT) * 2 + wr) * 16384;                                \
    const int bb_ = 65536 + ((SLOT) * 2 + (wc >> 1)) * 16384;                 \
    bf16x8 Bf[4][2], AfA[2][2], AfB[2][2];                                    \
    /* p0 */                                                                  \
    DS_READ_BF(); DS_READ_A(AfA, 0); DS_READ_A(AfB, 1);                       \
    if (SA) STAGE_A(0, (KT) + 1, (SLOT) ^ 1);                                 \
    FENCE();                                                                  \
    __builtin_amdgcn_s_barrier();                                             \
    MFMA16(0, AfA);                                                           \
    __builtin_amdgcn_s_barrier();                                             \
    FENCE();                                                                  \
    /* p1 */                                                                  \
    DS_READ_A(AfA, 2);                                                        \
    if (SA) STAGE_A(1, (KT) + 1, (SLOT) ^ 1);                                 \
    FENCE();                                                                  \
    __builtin_amdgcn_s_barrier();                                             \
    MFMA16(1, AfB);                                                           \
    __builtin_amdgcn_s_barrier();                                             \
    FENCE();                                                                  \
    /* p2 */                                                                  \
    DS_READ_A(AfB, 3);                                                        \
    if (SB) STAGE_B(0, (KT) + 2, (SLOT));                                     \
    FENCE();                                                                  \
    __builtin_amdgcn_s_barrier();                                             \
    MFMA16(2, AfA);                                                           \
    __builtin_amdgcn_s_barrier();                                             \
    FENCE();                                                                  \
    /* p3 */                                                                  \
    if (SB) STAGE_B(1, (KT) + 2, (SLOT));                                     \
    FENCE();                                                                  \
    __builtin_amdgcn_s_barrier();                                             \
    MFMA16(3, AfB);                                                           \
    TAILWAIT                                                                  \
    __builtin_amdgcn_s_barrier();                                             \
    FENCE();                                                                  \
  }

__global__ __launch_bounds__(512, 2) void qkv_gemm256(
    const uint16_t* __restrict__ A, const uint16_t* __restrict__ W,
    const float* __restrict__ Bq, const float* __restrict__ Bk,
    const float* __restrict__ Bv, float* __restrict__ C,
    int M, int N, int K)
{
    (void)M;
    extern __shared__ uint16_t lds[];
    const int t = threadIdx.x;
    const int lane = t & 63, wid = t >> 6;
    const int wr = wid >> 2, wc = wid & 3;          // 2 x 4 wave grid
    const int fr = lane & 15;
    const int fq2 = (lane >> 4) * 16;               // k-frag byte offset {0,16,32,48}

    // T1: XCD swizzle + within-XCD band reorder (R5: FETCH 320->147MB).
    const int nbt = N >> 8;                         // 24 col-tiles
    const int nwg = gridDim.x;
    int mb, nb;
    if ((nwg & 7) == 0) {
        const int cpx = nwg >> 3;                   // 96 tiles per XCD
        const int xcd = blockIdx.x & 7, ti = blockIdx.x >> 3;
        if (cpx % nbt == 0 && (nbt & 7) == 0) {
            const int band = ti >> 5, r = ti & 31;
            mb = xcd * (cpx / nbt) + (r >> 3);
            nb = (band << 3) + (r & 7);
        } else {
            const int swz = xcd * cpx + ti;
            mb = swz / nbt; nb = swz % nbt;
        }
    } else {
        mb = blockIdx.x / nbt; nb = blockIdx.x % nbt;
    }

    // read-side swizzle: logical byte q -> LDS byte q ^ ((row&7)<<4)
    // (R5: SQ_LDS_BANK_CONFLICT == 0 with this mapping).
    const int kbase = fq2 ^ ((fr & 7) << 4);
    const int aoff = fr * 128 + kbase;
    const int boff = ((wc & 1) * 64 + fr) * 128 + kbase;

    // write-side pre-swizzled global source (same involution).
    const int srow = t >> 3;
    const int scol = (((t & 7) ^ ((t >> 3) & 7)) << 3);
    const uint16_t* gA = A + (size_t)(mb * 256 + srow) * K + scol;
    const uint16_t* gB = W + (size_t)(nb * 256 + srow) * K + scol;

    f32x4 acc[8][4] = {};
    const int NT = K >> 6;                          // 32 K-tiles

    // prologue: B(0)->Bslot0, A(0)->Aslot0, B(1)->Bslot1; keep B(1) in flight
    STAGE_B(0, 0, 0); STAGE_B(1, 0, 0);
    STAGE_A(0, 0, 0); STAGE_A(1, 0, 0);
    STAGE_B(0, 1, 1); STAGE_B(1, 1, 1);
    asm volatile("s_waitcnt vmcnt(4)" ::: "memory");
    __builtin_amdgcn_s_barrier();
    FENCE();

#pragma unroll 1
    for (int i = 0; i < (NT >> 1) - 1; ++i) {
        const int k0 = i << 1;
        KTILE(0, k0,     1, 1, asm volatile("s_waitcnt vmcnt(4)" ::: "memory");)
        KTILE(1, k0 + 1, 1, 1, asm volatile("s_waitcnt vmcnt(4)" ::: "memory");)
    }
    // tail: tile NT-2 stages A(NT-1) only, drain; tile NT-1 pure compute
    KTILE(0, NT - 2, 1, 0, asm volatile("s_waitcnt vmcnt(0)" ::: "memory");)
    KTILE(1, NT - 1, 0, 0, )

    // epilogue: C/D layout row=(lane>>4)*4+reg, col=lane&15. fp32 stores + bias.
    const int r0 = mb * 256 + wr * 128 + (lane >> 4) * 4;
    const int c0 = nb * 256 + wc * 64 + fr;
    const float* bp = (nb < 8) ? Bq : (nb < 16) ? Bk : Bv;
    const int cb = (nb & 7) * 256 + wc * 64 + fr;
    float bj[4];
#pragma unroll
    for (int j = 0; j < 4; ++j) bj[j] = bp[cb + j * 16];
#pragma unroll
    for (int i = 0; i < 8; ++i)
#pragma unroll
        for (int j = 0; j < 4; ++j)
#pragma unroll
            for (int r = 0; r < 4; ++r)
                C[(size_t)(r0 + i * 16 + r) * N + c0 + j * 16] = acc[i][j][r] + bj[j];
}

extern "C" void kernel_launch(void* const* d_in, const int* in_sizes, int n_in,
                              void* d_out, int out_size, void* d_ws, size_t ws_size,
                              hipStream_t stream) {
    const float* x  = (const float*)d_in[0];
    const float* nw = (const float*)d_in[1];
    const float* nb = (const float*)d_in[2];
    const float* wq = (const float*)d_in[3];
    const float* bq = (const float*)d_in[4];
    const float* wk = (const float*)d_in[5];
    const float* bk = (const float*)d_in[6];
    const float* wv = (const float*)d_in[7];
    const float* bv = (const float*)d_in[8];

    const int D = in_sizes[1];        // 2048
    const int M = in_sizes[0] / D;    // 8192 (B*S)
    const int N = 3 * D;              // 6144

    static bool attr_done = false;
    if (!attr_done) {
        hipFuncSetAttribute((const void*)qkv_gemm256,
                            hipFuncAttributeMaxDynamicSharedMemorySize, 131072);
        attr_done = true;
    }

    // ws layout: [normed bf16: M*D] [Wcat bf16: N*D]
    uint16_t* normed = (uint16_t*)d_ws;
    uint16_t* wcat   = normed + (size_t)M * D;

    ln_kernel<<<M, 256, 0, stream>>>(x, nw, nb, normed, D);
    wcvt_kernel<<<((size_t)N * D) / (256 * 8), 256, 0, stream>>>(wq, wk, wv, wcat);
    const int grid = (M / 256) * (N / 256);          // 768, %8==0
    qkv_gemm256<<<grid, 512, 131072, stream>>>(normed, wcat, bq, bk, bv,
                                               (float*)d_out, M, N, D);
}